// Round 15
// baseline (62.011 us; speedup 1.0000x reference)
//
#include <hip/hip_runtime.h>

#define BATCH 8
#define ROWS 1536
#define KCLS 32
#define NTOT (BATCH*ROWS)        // 12288
#define ELEMS (NTOT*16)          // 196608
#define SSTRIDE 3073             // padded prefix-sum stride per batch
#define BIGF 1.0e30f

// workspace layout (float offsets)
enum : int {
  WS_Z     = 0,                          // [8][1536][16]
  WS_XS    = WS_Z + NTOT*16,             // [8][1536]
  WS_S     = WS_XS + NTOT,               // [8][3073] padded
  WS_DESC  = WS_S + BATCH*SSTRIDE,       // [8][1536] int
  WS_ASCP  = WS_DESC + NTOT,             // [4][12288] int
  WS_DSCP  = WS_ASCP + 4*NTOT,           // [4][12288] int
  WS_GPART = WS_DSCP + 4*NTOT,           // max([8][96][512] cpart, [8][8][1536] k8a)
  WS_LOSSP = WS_GPART + BATCH*96*512,    // [768]
};
#define WS_CPART WS_GPART   // disjoint lifetimes: cpart k1->kcount, gpart k8a->k8b

// LDS weight layout (float offsets)
#define LW1  0
#define LB1  512
#define LW2  544
#define LB2  2592
#define LMW  2656
#define LMB  3680
#define LDW1 3696
#define LDB1 4208
#define LDW2 4240
#define LDB2 4752
#define LTOT 4768

// activation features per row (float offsets, all multiples of 4)
#define AX   0
#define AH1  16
#define AH2  48
#define AZ   112
#define AR1  128
#define AREC 144
#define ASTRIDE 164   // row stride in floats; 164%32=4 -> 2-way max conflicts

#define RPB 16        // rows per block in k1

// One layer slice with 4 accumulator banks (one per float4 lane of the input)
template<int IN_BASE, int IN_N, int OUT_BASE, int OUT_PW, int OUT_TOT,
         int WOFF, int BOFF, bool RELU>
__device__ __forceinline__ void layerw(float* __restrict__ act,
                                       const float* __restrict__ wsh,
                                       int lrow, int fway)
{
  const int o0 = fway * OUT_PW;
  float a0[OUT_PW], a1[OUT_PW], a2[OUT_PW], a3[OUT_PW];
#pragma unroll
  for (int j = 0; j < OUT_PW; ++j) {
    a0[j] = wsh[BOFF + o0 + j];
    a1[j] = 0.f; a2[j] = 0.f; a3[j] = 0.f;
  }

  const float4* arow = reinterpret_cast<const float4*>(&act[lrow*ASTRIDE + IN_BASE]);
#pragma unroll
  for (int i4 = 0; i4 < IN_N/4; ++i4) {
    const float4 sv = arow[i4];
    const float* wp0 = &wsh[WOFF + (i4*4 + 0)*OUT_TOT + o0];
    const float* wp1 = &wsh[WOFF + (i4*4 + 1)*OUT_TOT + o0];
    const float* wp2 = &wsh[WOFF + (i4*4 + 2)*OUT_TOT + o0];
    const float* wp3 = &wsh[WOFF + (i4*4 + 3)*OUT_TOT + o0];
    if constexpr (OUT_PW == 1) {
      a0[0] = fmaf(sv.x, wp0[0], a0[0]);
      a1[0] = fmaf(sv.y, wp1[0], a1[0]);
      a2[0] = fmaf(sv.z, wp2[0], a2[0]);
      a3[0] = fmaf(sv.w, wp3[0], a3[0]);
    } else if constexpr (OUT_PW == 2) {
      const float2 w0 = *reinterpret_cast<const float2*>(wp0);
      const float2 w1 = *reinterpret_cast<const float2*>(wp1);
      const float2 w2 = *reinterpret_cast<const float2*>(wp2);
      const float2 w3 = *reinterpret_cast<const float2*>(wp3);
      a0[0] = fmaf(sv.x, w0.x, a0[0]); a0[1] = fmaf(sv.x, w0.y, a0[1]);
      a1[0] = fmaf(sv.y, w1.x, a1[0]); a1[1] = fmaf(sv.y, w1.y, a1[1]);
      a2[0] = fmaf(sv.z, w2.x, a2[0]); a2[1] = fmaf(sv.z, w2.y, a2[1]);
      a3[0] = fmaf(sv.w, w3.x, a3[0]); a3[1] = fmaf(sv.w, w3.y, a3[1]);
    } else {
#pragma unroll
      for (int q = 0; q < OUT_PW/4; ++q) {
        const float4 w0 = reinterpret_cast<const float4*>(wp0)[q];
        const float4 w1 = reinterpret_cast<const float4*>(wp1)[q];
        const float4 w2 = reinterpret_cast<const float4*>(wp2)[q];
        const float4 w3 = reinterpret_cast<const float4*>(wp3)[q];
        a0[q*4+0] = fmaf(sv.x, w0.x, a0[q*4+0]);
        a0[q*4+1] = fmaf(sv.x, w0.y, a0[q*4+1]);
        a0[q*4+2] = fmaf(sv.x, w0.z, a0[q*4+2]);
        a0[q*4+3] = fmaf(sv.x, w0.w, a0[q*4+3]);
        a1[q*4+0] = fmaf(sv.y, w1.x, a1[q*4+0]);
        a1[q*4+1] = fmaf(sv.y, w1.y, a1[q*4+1]);
        a1[q*4+2] = fmaf(sv.y, w1.z, a1[q*4+2]);
        a1[q*4+3] = fmaf(sv.y, w1.w, a1[q*4+3]);
        a2[q*4+0] = fmaf(sv.z, w2.x, a2[q*4+0]);
        a2[q*4+1] = fmaf(sv.z, w2.y, a2[q*4+1]);
        a2[q*4+2] = fmaf(sv.z, w2.z, a2[q*4+2]);
        a2[q*4+3] = fmaf(sv.z, w2.w, a2[q*4+3]);
        a3[q*4+0] = fmaf(sv.w, w3.x, a3[q*4+0]);
        a3[q*4+1] = fmaf(sv.w, w3.y, a3[q*4+1]);
        a3[q*4+2] = fmaf(sv.w, w3.z, a3[q*4+2]);
        a3[q*4+3] = fmaf(sv.w, w3.w, a3[q*4+3]);
      }
    }
  }

  float* orow = &act[lrow*ASTRIDE + OUT_BASE + o0];
  if constexpr (OUT_PW == 1) {
    float v = (a0[0] + a1[0]) + (a2[0] + a3[0]);
    orow[0] = RELU ? fmaxf(v, 0.f) : v;
  } else if constexpr (OUT_PW == 2) {
    float2 v;
    v.x = (a0[0] + a1[0]) + (a2[0] + a3[0]);
    v.y = (a0[1] + a1[1]) + (a2[1] + a3[1]);
    if (RELU) { v.x = fmaxf(v.x, 0.f); v.y = fmaxf(v.y, 0.f); }
    *reinterpret_cast<float2*>(orow) = v;
  } else {
#pragma unroll
    for (int q = 0; q < OUT_PW/4; ++q) {
      float4 v;
      v.x = (a0[q*4+0] + a1[q*4+0]) + (a2[q*4+0] + a3[q*4+0]);
      v.y = (a0[q*4+1] + a1[q*4+1]) + (a2[q*4+1] + a3[q*4+1]);
      v.z = (a0[q*4+2] + a1[q*4+2]) + (a2[q*4+2] + a3[q*4+2]);
      v.w = (a0[q*4+3] + a1[q*4+3]) + (a2[q*4+3] + a3[q*4+3]);
      if (RELU) {
        v.x = fmaxf(v.x, 0.f); v.y = fmaxf(v.y, 0.f);
        v.z = fmaxf(v.z, 0.f); v.w = fmaxf(v.w, 0.f);
      }
      reinterpret_cast<float4*>(orow)[q] = v;
    }
  }
}

// ---- K1: autoencoder + z + loss partials + fused center partials ----
__global__ __launch_bounds__(256, 4) void k1_ae(
    const float* __restrict__ table,
    const float* __restrict__ w1, const float* __restrict__ b1,
    const float* __restrict__ w2, const float* __restrict__ b2,
    const float* __restrict__ mw, const float* __restrict__ mb,
    const float* __restrict__ dw1, const float* __restrict__ db1,
    const float* __restrict__ dw2, const float* __restrict__ db2,
    const int* __restrict__ labels,
    float* __restrict__ ws)
{
  const int tid  = threadIdx.x;
  const int lrow = tid & (RPB-1);
  const int fway = tid >> 4;
  const int blk  = blockIdx.x;           // 0..767
  const int b    = blk / 96;
  const int ch   = blk % 96;

  __shared__ float wsh[LTOT];
  __shared__ float act[RPB * ASTRIDE];
  __shared__ int   lbl[RPB];
  __shared__ float lred[4];

  {
    float4* d4 = reinterpret_cast<float4*>(wsh);
#define CPY(off, src, nf4) \
    { const float4* p = reinterpret_cast<const float4*>(src); \
      for (int t = tid; t < (nf4); t += 256) d4[(off)/4 + t] = p[t]; }
    CPY(LW1,  w1,  128) CPY(LB1,  b1,  8)  CPY(LW2,  w2,  512)
    CPY(LB2,  b2,  16)  CPY(LMW,  mw,  256) CPY(LMB,  mb,  4)
    CPY(LDW1, dw1, 128) CPY(LDB1, db1, 8)  CPY(LDW2, dw2, 128)
    CPY(LDB2, db2, 4)
#undef CPY
    if (tid < RPB) lbl[tid] = labels[ch * RPB + tid];
    if (tid < RPB*4) {
      const float4 v = reinterpret_cast<const float4*>(table)[blk*(RPB*4) + tid];
      reinterpret_cast<float4*>(act)[(tid >> 2)*(ASTRIDE/4) + (tid & 3)] = v;
    }
  }
  __syncthreads();

  layerw<AX,  16, AH1, 2, 32, LW1,  LB1,  true >(act, wsh, lrow, fway);
  __syncthreads();
  layerw<AH1, 32, AH2, 4, 64, LW2,  LB2,  true >(act, wsh, lrow, fway);
  __syncthreads();
  layerw<AH2, 64, AZ,  1, 16, LMW,  LMB,  false>(act, wsh, lrow, fway);
  __syncthreads();

  if (tid < RPB*4) {
    const float4 zv =
      reinterpret_cast<const float4*>(act)[(tid >> 2)*(ASTRIDE/4) + (AZ/4) + (tid & 3)];
    reinterpret_cast<float4*>(ws + WS_Z)[blk*(RPB*4) + tid] = zv;
  }

  layerw<AZ,  16, AR1, 2, 32, LDW1, LDB1, true >(act, wsh, lrow, fway);
  __syncthreads();
  layerw<AR1, 32, AREC,1, 16, LDW2, LDB2, true >(act, wsh, lrow, fway);
  __syncthreads();

  {
    const float d = act[lrow*ASTRIDE + AREC + fway] - act[lrow*ASTRIDE + AX + fway];
    float ls = d * d;
    for (int off = 32; off > 0; off >>= 1) ls += __shfl_down(ls, off);
    if ((tid & 63) == 0) lred[tid >> 6] = ls;
    __syncthreads();
    if (tid == 0) ws[WS_LOSSP + blk] = (lred[0] + lred[1]) + (lred[2] + lred[3]);
  }

  {
    float a0 = 0.f, a1 = 0.f;
    const int d0 = tid & 15, k0 = tid >> 4;
    const int k1c = k0 + 16;
#pragma unroll
    for (int rr = 0; rr < RPB; ++rr) {
      const int lb = lbl[rr];
      const float zv = act[rr*ASTRIDE + AZ + d0];
      a0 += (lb == k0)  ? zv : 0.f;
      a1 += (lb == k1c) ? zv : 0.f;
    }
    ws[WS_CPART + (b*96 + ch)*512 + tid]       = a0;
    ws[WS_CPART + (b*96 + ch)*512 + 256 + tid] = a1;
  }
}

// ---- KCOUNT: counts + centers (direct 96-sum, L2-resident) + d2 (regs) +
//      exact minmax + scores + stable rank counts. 192 blocks; all blocks of
//      a batch compute bit-identical centers/scores (same code, data, order).
__global__ __launch_bounds__(256) void kcount(const int* __restrict__ labels,
                                              float* __restrict__ ws,
                                              float* __restrict__ out)
{
  const int bi = blockIdx.x;
  const int jb = bi & 3, rb = (bi >> 2) % 6, b = bi / 24;
  const int tid = threadIdx.x;

  alignas(16) __shared__ float s_l[ROWS];
  __shared__ float cent[512];
  __shared__ float rmn[256], rmx[256];
  __shared__ int cnt[KCLS];

  if (tid < KCLS) cnt[tid] = 0;
  __syncthreads();

  int lbv[6];
#pragma unroll
  for (int c = 0; c < 6; ++c) {
    lbv[c] = labels[c*256 + tid];
    atomicAdd(&cnt[lbv[c]], 1);
  }

  // centers: direct 96-chunk sum, 4 independent chains (2 per output elem)
  float s1a = 0.f, s1b = 0.f, s2a = 0.f, s2b = 0.f;
  {
    const float* cp = ws + WS_CPART + (b*96)*512;
#pragma unroll 4
    for (int c = 0; c < 96; c += 2) {
      s1a += cp[c*512 + tid];
      s1b += cp[(c+1)*512 + tid];
      s2a += cp[c*512 + 256 + tid];
      s2b += cp[(c+1)*512 + 256 + tid];
    }
  }
  __syncthreads();   // cnt ready
  {
    int cn1 = cnt[tid >> 4];         cn1 = cn1 > 1 ? cn1 : 1;
    int cn2 = cnt[(tid + 256) >> 4]; cn2 = cn2 > 1 ? cn2 : 1;
    cent[tid]       = (s1a + s1b) / (float)cn1;
    cent[tid + 256] = (s2a + s2b) / (float)cn2;
  }
  __syncthreads();

  // d2 (6 rows/thread, registers) + exact block min/max
  float dv[6];
  float tmn = 3.0e38f, tmx = -3.0e38f;
#pragma unroll
  for (int c = 0; c < 6; ++c) {
    const int r = c*256 + tid;
    const float4* zp = reinterpret_cast<const float4*>(ws + WS_Z + (b*ROWS + r)*16);
    const float4* cq = reinterpret_cast<const float4*>(&cent[lbv[c]*16]);
    float s = 0.f;
#pragma unroll
    for (int q = 0; q < 4; ++q) {
      float4 zv = zp[q], cv = cq[q];
      float d0 = zv.x - cv.x, d1 = zv.y - cv.y, d2_ = zv.z - cv.z, d3 = zv.w - cv.w;
      s += d0*d0 + d1*d1 + d2_*d2_ + d3*d3;
    }
    dv[c] = s / 16.f;
    tmn = fminf(tmn, dv[c]); tmx = fmaxf(tmx, dv[c]);
  }
  rmn[tid] = tmn; rmx[tid] = tmx;
  __syncthreads();
  for (int off = 128; off > 0; off >>= 1) {
    if (tid < off) {
      rmn[tid] = fminf(rmn[tid], rmn[tid + off]);
      rmx[tid] = fmaxf(rmx[tid], rmx[tid + off]);
    }
    __syncthreads();
  }
  const float mn = rmn[0], mx = rmx[0];

  // scores
#pragma unroll
  for (int c = 0; c < 6; ++c) {
    const int r = c*256 + tid;
    const float sc = (dv[c] - mn) / (mx - mn) + (float)lbv[c];
    s_l[r] = sc;
    if (jb == 0 && c == rb) out[2*NTOT + b*ROWS + r] = sc;
  }
  __syncthreads();

  // stable rank counting for this block's (rb, jb) slice
  const int r0 = rb*256 + tid;
  const float si = s_l[r0];
  int asc = 0, dsc = 0;
  const int j0 = jb*384;
  const float4* s4p = reinterpret_cast<const float4*>(&s_l[j0]);
#pragma unroll 4
  for (int kk = 0; kk < 96; ++kk) {
    const float4 s4 = s4p[kk];
    const int j = j0 + kk*4;
    const bool t0 = (s4.x == si && j   < r0);
    const bool t1 = (s4.y == si && j+1 < r0);
    const bool t2 = (s4.z == si && j+2 < r0);
    const bool t3 = (s4.w == si && j+3 < r0);
    asc += (s4.x < si || t0) ? 1 : 0;
    asc += (s4.y < si || t1) ? 1 : 0;
    asc += (s4.z < si || t2) ? 1 : 0;
    asc += (s4.w < si || t3) ? 1 : 0;
    dsc += (s4.x > si || t0) ? 1 : 0;
    dsc += (s4.y > si || t1) ? 1 : 0;
    dsc += (s4.z > si || t2) ? 1 : 0;
    dsc += (s4.w > si || t3) ? 1 : 0;
  }
  int* wsi = reinterpret_cast<int*>(ws);
  wsi[WS_ASCP + jb*NTOT + b*ROWS + r0] = asc;
  wsi[WS_DSCP + jb*NTOT + b*ROWS + r0] = dsc;

  // loss reduce rides at the tail of block 0
  if (bi == 0) {
    __syncthreads();
    rmn[tid] = ws[WS_LOSSP + tid] + ws[WS_LOSSP + 256 + tid] + ws[WS_LOSSP + 512 + tid];
    __syncthreads();
    for (int off = 128; off > 0; off >>= 1) {
      if (tid < off) rmn[tid] += rmn[tid + off];
      __syncthreads();
    }
    if (tid == 0) out[3*NTOT] = rmn[0] / (float)ELEMS;
  }
}

// ------- K67: finalize counts -> rank_idx; smn/smx; xs scatter; scan -> S ----
__global__ __launch_bounds__(256) void k67(const int* __restrict__ bsp,
                                           float* __restrict__ ws,
                                           float* __restrict__ out)
{
  const int b = blockIdx.x, tid = threadIdx.x;
  const int lane = tid & 63, wav = tid >> 6;
  __shared__ float xs_l[ROWS];
  __shared__ float rmn[256], rmx[256];
  __shared__ float wtot[4];
  const int* wsi = reinterpret_cast<const int*>(ws);
  int* wsw = reinterpret_cast<int*>(ws);
  const int BS = *bsp;

  int dscv[6];
  float sv[6];
  float tmn = 3.0e38f, tmx = -3.0e38f;
#pragma unroll
  for (int c = 0; c < 6; ++c) {
    const int r = c*256 + tid;
    const int idx = b*ROWS + r;
    int asc = 0, dsc = 0;
#pragma unroll
    for (int jb = 0; jb < 4; ++jb) {
      asc += wsi[WS_ASCP + jb*NTOT + idx];
      dsc += wsi[WS_DSCP + jb*NTOT + idx];
    }
    out[NTOT + idx] = (float)(asc / BS + 1);
    wsw[WS_DESC + idx] = dsc;
    dscv[c] = dsc;
    const float sc = out[2*NTOT + idx];
    sv[c] = sc;
    tmn = fminf(tmn, sc); tmx = fmaxf(tmx, sc);
  }
  rmn[tid] = tmn; rmx[tid] = tmx;
  __syncthreads();
  for (int off = 128; off > 0; off >>= 1) {
    if (tid < off) {
      rmn[tid] = fminf(rmn[tid], rmn[tid + off]);
      rmx[tid] = fmaxf(rmx[tid], rmx[tid + off]);
    }
    __syncthreads();
  }
  const float smn = rmn[0], smx = rmx[0];
  __syncthreads();

#pragma unroll
  for (int c = 0; c < 6; ++c) {
    const float scl = (sv[c] - smn) / (smx - smn) * 8.0f;
    xs_l[dscv[c]] = scl / 0.01f;
  }
  __syncthreads();

  const int base = tid * 6;
  float y[6], own = 0.f;
#pragma unroll
  for (int u = 0; u < 6; ++u) {
    ws[WS_XS + b*ROWS + base + u] = xs_l[base + u];
    y[u] = (float)(ROWS - (base + u)) - xs_l[base + u];
    own += y[u];
  }
  float v = own;
#pragma unroll
  for (int d = 1; d < 64; d <<= 1) {
    float o = __shfl_up(v, d);
    if (lane >= d) v += o;
  }
  if (lane == 63) wtot[wav] = v;
  __syncthreads();
  float wpre = 0.f;
  for (int w = 0; w < wav; ++w) wpre += wtot[w];
  float run = wpre + (v - own);
  float* S = ws + WS_S + b*SSTRIDE;
#pragma unroll
  for (int u = 0; u < 6; ++u) { S[base + u] = run; run += y[u]; }
  if (tid == 255) S[ROWS] = run;
#pragma unroll
  for (int u = 0; u < 6; ++u) S[ROWS + 1 + tid*6 + u] = BIGF;
}

// ---------------- K8a: chunk-partial minima of segment averages --------------
__global__ __launch_bounds__(256) void k8a(float* __restrict__ ws)
{
  const int bi = blockIdx.x;
  const int c = bi & 7, ib = (bi >> 3) % 6, b = bi / 48;
  const int tid = threadIdx.x;
  __shared__ float Sseg[448];
  __shared__ float invl[192];
  const float* S = ws + WS_S + b*SSTRIDE;
  const int ibase = ib*256;
  const int segbase = ibase + c*192 + 1;
  Sseg[tid] = S[segbase + tid];
  if (tid < 192) {
    Sseg[256 + tid] = S[segbase + 256 + tid];
    invl[tid] = 1.0f / (float)(c*192 + tid + 1);
  }
  __syncthreads();
  const int i = ibase + tid;
  const float Si = S[i];
  float gm = 3.0e38f;
#pragma unroll 8
  for (int k = 0; k < 192; ++k)
    gm = fminf(gm, (Sseg[tid + k] - Si) * invl[k]);
  ws[WS_GPART + (b*8 + c)*ROWS + i] = gm;
}

// --------- K8b: reduce partials, prefix-max (isotonic), final ranks ----------
__global__ __launch_bounds__(768) void k8b(float* __restrict__ ws,
                                           float* __restrict__ out)
{
  const int b = blockIdx.x, tid = threadIdx.x;
  const int lane = tid & 63, wav = tid >> 6;
  __shared__ float g[ROWS];
  __shared__ float wtot[12];
  for (int t = tid; t < ROWS; t += 768) {
    float gm = 3.0e38f;
#pragma unroll
    for (int c = 0; c < 8; ++c)
      gm = fminf(gm, ws[WS_GPART + (b*8 + c)*ROWS + t]);
    g[t] = gm;
  }
  __syncthreads();
  const float a = g[2*tid], cc = g[2*tid + 1];
  float v = fmaxf(a, cc);
#pragma unroll
  for (int d = 1; d < 64; d <<= 1) {
    float o = __shfl_up(v, d);
    if (lane >= d) v = fmaxf(v, o);
  }
  if (lane == 63) wtot[wav] = v;
  __syncthreads();
  float wpre = -3.0e38f;
  for (int w = 0; w < wav; ++w) wpre = fmaxf(wpre, wtot[w]);
  float lex = __shfl_up(v, 1);
  if (lane == 0) lex = -3.0e38f;
  const float excl = fmaxf(wpre, lex);
  const float i0 = fmaxf(excl, a);
  const float i1 = fmaxf(i0, cc);
  g[2*tid] = i0; g[2*tid + 1] = i1;
  __syncthreads();
  const float* xs = ws + WS_XS + b*ROWS;
  const int* desc = reinterpret_cast<const int*>(ws) + WS_DESC + b*ROWS;
  for (int t = tid; t < ROWS; t += 768) {
    const int dr = desc[t];
    out[b*ROWS + t] = xs[dr] + g[dr];
  }
}

extern "C" void kernel_launch(void* const* d_in, const int* in_sizes, int n_in,
                              void* d_out, int out_size, void* d_ws, size_t ws_size,
                              hipStream_t stream) {
  const float* table = (const float*)d_in[0];
  const float* w1  = (const float*)d_in[1];
  const float* b1  = (const float*)d_in[2];
  const float* w2  = (const float*)d_in[3];
  const float* b2  = (const float*)d_in[4];
  const float* mw  = (const float*)d_in[5];
  const float* mb  = (const float*)d_in[6];
  const float* dw1 = (const float*)d_in[7];
  const float* db1 = (const float*)d_in[8];
  const float* dw2 = (const float*)d_in[9];
  const float* db2 = (const float*)d_in[10];
  const int* labels = (const int*)d_in[11];
  const int* bsp    = (const int*)d_in[12];
  float* out = (float*)d_out;
  float* ws  = (float*)d_ws;

  k1_ae<<<768, 256, 0, stream>>>(table, w1, b1, w2, b2, mw, mb, dw1, db1, dw2, db2, labels, ws);
  kcount<<<192, 256, 0, stream>>>(labels, ws, out);
  k67<<<8, 256, 0, stream>>>(bsp, ws, out);
  k8a<<<384, 256, 0, stream>>>(ws);
  k8b<<<8, 768, 0, stream>>>(ws, out);
}

// Round 16
// 56.735 us; speedup vs baseline: 1.0930x; 1.0930x over previous
//
#include <hip/hip_runtime.h>

#define BATCH 8
#define ROWS 1536
#define KCLS 32
#define NTOT (BATCH*ROWS)        // 12288
#define ELEMS (NTOT*16)          // 196608
#define BIGF 1.0e30f

// workspace layout (float offsets)
enum : int {
  WS_Z     = 0,                          // [8][1536][16]
  WS_XS    = WS_Z + NTOT*16,             // [8][1536]
  WS_DESC  = WS_XS + NTOT,               // [8][1536] int
  WS_GPART = WS_DESC + NTOT,             // max([8][96][512] cpart, [8][8][1536] gpart)
  WS_LOSSP = WS_GPART + BATCH*96*512,    // [768]
};
#define WS_CPART WS_GPART   // disjoint lifetimes: cpart k1->kranks, gpart k8a->k8b

// LDS weight layout (float offsets)
#define LW1  0
#define LB1  512
#define LW2  544
#define LB2  2592
#define LMW  2656
#define LMB  3680
#define LDW1 3696
#define LDB1 4208
#define LDW2 4240
#define LDB2 4752
#define LTOT 4768

// activation features per row (float offsets, all multiples of 4)
#define AX   0
#define AH1  16
#define AH2  48
#define AZ   112
#define AR1  128
#define AREC 144
#define ASTRIDE 164   // row stride in floats; 164%32=4 -> 2-way max conflicts

#define RPB 16        // rows per block in k1

// One layer slice with 4 accumulator banks (one per float4 lane of the input)
template<int IN_BASE, int IN_N, int OUT_BASE, int OUT_PW, int OUT_TOT,
         int WOFF, int BOFF, bool RELU>
__device__ __forceinline__ void layerw(float* __restrict__ act,
                                       const float* __restrict__ wsh,
                                       int lrow, int fway)
{
  const int o0 = fway * OUT_PW;
  float a0[OUT_PW], a1[OUT_PW], a2[OUT_PW], a3[OUT_PW];
#pragma unroll
  for (int j = 0; j < OUT_PW; ++j) {
    a0[j] = wsh[BOFF + o0 + j];
    a1[j] = 0.f; a2[j] = 0.f; a3[j] = 0.f;
  }

  const float4* arow = reinterpret_cast<const float4*>(&act[lrow*ASTRIDE + IN_BASE]);
#pragma unroll
  for (int i4 = 0; i4 < IN_N/4; ++i4) {
    const float4 sv = arow[i4];
    const float* wp0 = &wsh[WOFF + (i4*4 + 0)*OUT_TOT + o0];
    const float* wp1 = &wsh[WOFF + (i4*4 + 1)*OUT_TOT + o0];
    const float* wp2 = &wsh[WOFF + (i4*4 + 2)*OUT_TOT + o0];
    const float* wp3 = &wsh[WOFF + (i4*4 + 3)*OUT_TOT + o0];
    if constexpr (OUT_PW == 1) {
      a0[0] = fmaf(sv.x, wp0[0], a0[0]);
      a1[0] = fmaf(sv.y, wp1[0], a1[0]);
      a2[0] = fmaf(sv.z, wp2[0], a2[0]);
      a3[0] = fmaf(sv.w, wp3[0], a3[0]);
    } else if constexpr (OUT_PW == 2) {
      const float2 w0 = *reinterpret_cast<const float2*>(wp0);
      const float2 w1 = *reinterpret_cast<const float2*>(wp1);
      const float2 w2 = *reinterpret_cast<const float2*>(wp2);
      const float2 w3 = *reinterpret_cast<const float2*>(wp3);
      a0[0] = fmaf(sv.x, w0.x, a0[0]); a0[1] = fmaf(sv.x, w0.y, a0[1]);
      a1[0] = fmaf(sv.y, w1.x, a1[0]); a1[1] = fmaf(sv.y, w1.y, a1[1]);
      a2[0] = fmaf(sv.z, w2.x, a2[0]); a2[1] = fmaf(sv.z, w2.y, a2[1]);
      a3[0] = fmaf(sv.w, w3.x, a3[0]); a3[1] = fmaf(sv.w, w3.y, a3[1]);
    } else {
#pragma unroll
      for (int q = 0; q < OUT_PW/4; ++q) {
        const float4 w0 = reinterpret_cast<const float4*>(wp0)[q];
        const float4 w1 = reinterpret_cast<const float4*>(wp1)[q];
        const float4 w2 = reinterpret_cast<const float4*>(wp2)[q];
        const float4 w3 = reinterpret_cast<const float4*>(wp3)[q];
        a0[q*4+0] = fmaf(sv.x, w0.x, a0[q*4+0]);
        a0[q*4+1] = fmaf(sv.x, w0.y, a0[q*4+1]);
        a0[q*4+2] = fmaf(sv.x, w0.z, a0[q*4+2]);
        a0[q*4+3] = fmaf(sv.x, w0.w, a0[q*4+3]);
        a1[q*4+0] = fmaf(sv.y, w1.x, a1[q*4+0]);
        a1[q*4+1] = fmaf(sv.y, w1.y, a1[q*4+1]);
        a1[q*4+2] = fmaf(sv.y, w1.z, a1[q*4+2]);
        a1[q*4+3] = fmaf(sv.y, w1.w, a1[q*4+3]);
        a2[q*4+0] = fmaf(sv.z, w2.x, a2[q*4+0]);
        a2[q*4+1] = fmaf(sv.z, w2.y, a2[q*4+1]);
        a2[q*4+2] = fmaf(sv.z, w2.z, a2[q*4+2]);
        a2[q*4+3] = fmaf(sv.z, w2.w, a2[q*4+3]);
        a3[q*4+0] = fmaf(sv.w, w3.x, a3[q*4+0]);
        a3[q*4+1] = fmaf(sv.w, w3.y, a3[q*4+1]);
        a3[q*4+2] = fmaf(sv.w, w3.z, a3[q*4+2]);
        a3[q*4+3] = fmaf(sv.w, w3.w, a3[q*4+3]);
      }
    }
  }

  float* orow = &act[lrow*ASTRIDE + OUT_BASE + o0];
  if constexpr (OUT_PW == 1) {
    float v = (a0[0] + a1[0]) + (a2[0] + a3[0]);
    orow[0] = RELU ? fmaxf(v, 0.f) : v;
  } else if constexpr (OUT_PW == 2) {
    float2 v;
    v.x = (a0[0] + a1[0]) + (a2[0] + a3[0]);
    v.y = (a0[1] + a1[1]) + (a2[1] + a3[1]);
    if (RELU) { v.x = fmaxf(v.x, 0.f); v.y = fmaxf(v.y, 0.f); }
    *reinterpret_cast<float2*>(orow) = v;
  } else {
#pragma unroll
    for (int q = 0; q < OUT_PW/4; ++q) {
      float4 v;
      v.x = (a0[q*4+0] + a1[q*4+0]) + (a2[q*4+0] + a3[q*4+0]);
      v.y = (a0[q*4+1] + a1[q*4+1]) + (a2[q*4+1] + a3[q*4+1]);
      v.z = (a0[q*4+2] + a1[q*4+2]) + (a2[q*4+2] + a3[q*4+2]);
      v.w = (a0[q*4+3] + a1[q*4+3]) + (a2[q*4+3] + a3[q*4+3]);
      if (RELU) {
        v.x = fmaxf(v.x, 0.f); v.y = fmaxf(v.y, 0.f);
        v.z = fmaxf(v.z, 0.f); v.w = fmaxf(v.w, 0.f);
      }
      reinterpret_cast<float4*>(orow)[q] = v;
    }
  }
}

// ---- K1: autoencoder + z + loss partials + fused center partials ----
__global__ __launch_bounds__(256, 4) void k1_ae(
    const float* __restrict__ table,
    const float* __restrict__ w1, const float* __restrict__ b1,
    const float* __restrict__ w2, const float* __restrict__ b2,
    const float* __restrict__ mw, const float* __restrict__ mb,
    const float* __restrict__ dw1, const float* __restrict__ db1,
    const float* __restrict__ dw2, const float* __restrict__ db2,
    const int* __restrict__ labels,
    float* __restrict__ ws)
{
  const int tid  = threadIdx.x;
  const int lrow = tid & (RPB-1);
  const int fway = tid >> 4;
  const int blk  = blockIdx.x;           // 0..767
  const int b    = blk / 96;
  const int ch   = blk % 96;

  __shared__ float wsh[LTOT];
  __shared__ float act[RPB * ASTRIDE];
  __shared__ int   lbl[RPB];
  __shared__ float lred[4];

  {
    float4* d4 = reinterpret_cast<float4*>(wsh);
#define CPY(off, src, nf4) \
    { const float4* p = reinterpret_cast<const float4*>(src); \
      for (int t = tid; t < (nf4); t += 256) d4[(off)/4 + t] = p[t]; }
    CPY(LW1,  w1,  128) CPY(LB1,  b1,  8)  CPY(LW2,  w2,  512)
    CPY(LB2,  b2,  16)  CPY(LMW,  mw,  256) CPY(LMB,  mb,  4)
    CPY(LDW1, dw1, 128) CPY(LDB1, db1, 8)  CPY(LDW2, dw2, 128)
    CPY(LDB2, db2, 4)
#undef CPY
    if (tid < RPB) lbl[tid] = labels[ch * RPB + tid];
    if (tid < RPB*4) {
      const float4 v = reinterpret_cast<const float4*>(table)[blk*(RPB*4) + tid];
      reinterpret_cast<float4*>(act)[(tid >> 2)*(ASTRIDE/4) + (tid & 3)] = v;
    }
  }
  __syncthreads();

  layerw<AX,  16, AH1, 2, 32, LW1,  LB1,  true >(act, wsh, lrow, fway);
  __syncthreads();
  layerw<AH1, 32, AH2, 4, 64, LW2,  LB2,  true >(act, wsh, lrow, fway);
  __syncthreads();
  layerw<AH2, 64, AZ,  1, 16, LMW,  LMB,  false>(act, wsh, lrow, fway);
  __syncthreads();

  if (tid < RPB*4) {
    const float4 zv =
      reinterpret_cast<const float4*>(act)[(tid >> 2)*(ASTRIDE/4) + (AZ/4) + (tid & 3)];
    reinterpret_cast<float4*>(ws + WS_Z)[blk*(RPB*4) + tid] = zv;
  }

  layerw<AZ,  16, AR1, 2, 32, LDW1, LDB1, true >(act, wsh, lrow, fway);
  __syncthreads();
  layerw<AR1, 32, AREC,1, 16, LDW2, LDB2, true >(act, wsh, lrow, fway);
  __syncthreads();

  {
    const float d = act[lrow*ASTRIDE + AREC + fway] - act[lrow*ASTRIDE + AX + fway];
    float ls = d * d;
    for (int off = 32; off > 0; off >>= 1) ls += __shfl_down(ls, off);
    if ((tid & 63) == 0) lred[tid >> 6] = ls;
    __syncthreads();
    if (tid == 0) ws[WS_LOSSP + blk] = (lred[0] + lred[1]) + (lred[2] + lred[3]);
  }

  {
    float a0 = 0.f, a1 = 0.f;
    const int d0 = tid & 15, k0 = tid >> 4;
    const int k1c = k0 + 16;
#pragma unroll
    for (int rr = 0; rr < RPB; ++rr) {
      const int lb = lbl[rr];
      const float zv = act[rr*ASTRIDE + AZ + d0];
      a0 += (lb == k0)  ? zv : 0.f;
      a1 += (lb == k1c) ? zv : 0.f;
    }
    ws[WS_CPART + (b*96 + ch)*512 + tid]       = a0;
    ws[WS_CPART + (b*96 + ch)*512 + 256 + tid] = a1;
  }
}

// ---- KRANKS: counts + centers + d2 + scores + FULL stable rank counts
//      + rank_idx + DESC + xs scatter. 192 blocks = (batch x 24 row-groups
//      of 64 rows). Each block computes the full batch scores in LDS
//      (bit-identical across blocks), then finishes its own 64 rows.
__global__ __launch_bounds__(256) void kranks(const int* __restrict__ labels,
                                              const int* __restrict__ bsp,
                                              float* __restrict__ ws,
                                              float* __restrict__ out)
{
  const int bi = blockIdx.x;
  const int rg = bi % 24, b = bi / 24;
  const int tid = threadIdx.x;

  alignas(16) __shared__ float s_l[ROWS];
  __shared__ float cent[512];
  __shared__ float rmn[256], rmx[256];
  __shared__ int cnt[KCLS];

  if (tid < KCLS) cnt[tid] = 0;
  __syncthreads();

  int lbv[6];
#pragma unroll
  for (int c = 0; c < 6; ++c) {
    lbv[c] = labels[c*256 + tid];
    atomicAdd(&cnt[lbv[c]], 1);
  }

  // centers: direct 96-chunk sum, 4 independent chains
  float s1a = 0.f, s1b = 0.f, s2a = 0.f, s2b = 0.f;
  {
    const float* cp = ws + WS_CPART + (b*96)*512;
#pragma unroll 4
    for (int c = 0; c < 96; c += 2) {
      s1a += cp[c*512 + tid];
      s1b += cp[(c+1)*512 + tid];
      s2a += cp[c*512 + 256 + tid];
      s2b += cp[(c+1)*512 + 256 + tid];
    }
  }
  __syncthreads();   // cnt ready
  {
    int cn1 = cnt[tid >> 4];         cn1 = cn1 > 1 ? cn1 : 1;
    int cn2 = cnt[(tid + 256) >> 4]; cn2 = cn2 > 1 ? cn2 : 1;
    cent[tid]       = (s1a + s1b) / (float)cn1;
    cent[tid + 256] = (s2a + s2b) / (float)cn2;
  }
  __syncthreads();

  // d2 (6 rows/thread, registers) + exact block min/max
  float dv[6];
  float tmn = 3.0e38f, tmx = -3.0e38f;
#pragma unroll
  for (int c = 0; c < 6; ++c) {
    const int r = c*256 + tid;
    const float4* zp = reinterpret_cast<const float4*>(ws + WS_Z + (b*ROWS + r)*16);
    const float4* cq = reinterpret_cast<const float4*>(&cent[lbv[c]*16]);
    float s = 0.f;
#pragma unroll
    for (int q = 0; q < 4; ++q) {
      float4 zv = zp[q], cv = cq[q];
      float d0 = zv.x - cv.x, d1 = zv.y - cv.y, d2_ = zv.z - cv.z, d3 = zv.w - cv.w;
      s += d0*d0 + d1*d1 + d2_*d2_ + d3*d3;
    }
    dv[c] = s / 16.f;
    tmn = fminf(tmn, dv[c]); tmx = fmaxf(tmx, dv[c]);
  }
  rmn[tid] = tmn; rmx[tid] = tmx;
  __syncthreads();
  for (int off = 128; off > 0; off >>= 1) {
    if (tid < off) {
      rmn[tid] = fminf(rmn[tid], rmn[tid + off]);
      rmx[tid] = fmaxf(rmx[tid], rmx[tid + off]);
    }
    __syncthreads();
  }
  const float mn = rmn[0], mx = rmx[0];
  __syncthreads();

  // scores (whole batch in s_l); write out scores only for this block's rows
  tmn = 3.0e38f; tmx = -3.0e38f;
#pragma unroll
  for (int c = 0; c < 6; ++c) {
    const int r = c*256 + tid;
    const float sc = (dv[c] - mn) / (mx - mn) + (float)lbv[c];
    s_l[r] = sc;
    if (c*4 + (tid >> 6) == rg) out[2*NTOT + b*ROWS + r] = sc;
    tmn = fminf(tmn, sc); tmx = fmaxf(tmx, sc);
  }
  rmn[tid] = tmn; rmx[tid] = tmx;
  __syncthreads();
  for (int off = 128; off > 0; off >>= 1) {
    if (tid < off) {
      rmn[tid] = fminf(rmn[tid], rmn[tid + off]);
      rmx[tid] = fmaxf(rmx[tid], rmx[tid + off]);
    }
    __syncthreads();
  }
  const float smn = rmn[0], smx = rmx[0];

  // FULL stable rank counts for this block's 64 rows: 4 threads per row,
  // each covers a 384-wide quarter of j; exact integer shfl combine.
  const int row_local = tid >> 2, q = tid & 3;
  const int r0 = rg*64 + row_local;
  const float si = s_l[r0];
  int asc = 0, dsc = 0;
  {
    const int j0 = q*384;
    const float4* s4p = reinterpret_cast<const float4*>(&s_l[j0]);
#pragma unroll 4
    for (int kk = 0; kk < 96; ++kk) {
      const float4 s4 = s4p[kk];
      const int j = j0 + kk*4;
      const bool t0 = (s4.x == si && j   < r0);
      const bool t1 = (s4.y == si && j+1 < r0);
      const bool t2 = (s4.z == si && j+2 < r0);
      const bool t3 = (s4.w == si && j+3 < r0);
      asc += (s4.x < si || t0) ? 1 : 0;
      asc += (s4.y < si || t1) ? 1 : 0;
      asc += (s4.z < si || t2) ? 1 : 0;
      asc += (s4.w < si || t3) ? 1 : 0;
      dsc += (s4.x > si || t0) ? 1 : 0;
      dsc += (s4.y > si || t1) ? 1 : 0;
      dsc += (s4.z > si || t2) ? 1 : 0;
      dsc += (s4.w > si || t3) ? 1 : 0;
    }
  }
  asc += __shfl_xor(asc, 1); asc += __shfl_xor(asc, 2);
  dsc += __shfl_xor(dsc, 1); dsc += __shfl_xor(dsc, 2);
  if (q == 0) {
    const int BS = *bsp;
    const int idx = b*ROWS + r0;
    out[NTOT + idx] = (float)(asc / BS + 1);
    reinterpret_cast<int*>(ws)[WS_DESC + idx] = dsc;
    const float scl = (si - smn) / (smx - smn) * 8.0f;
    ws[WS_XS + b*ROWS + dsc] = scl / 0.01f;
  }

  // loss reduce rides at the tail of block 0
  if (bi == 0) {
    __syncthreads();
    rmn[tid] = ws[WS_LOSSP + tid] + ws[WS_LOSSP + 256 + tid] + ws[WS_LOSSP + 512 + tid];
    __syncthreads();
    for (int off = 128; off > 0; off >>= 1) {
      if (tid < off) rmn[tid] += rmn[tid + off];
      __syncthreads();
    }
    if (tid == 0) out[3*NTOT] = rmn[0] / (float)ELEMS;
  }
}

// ---- K8a': redundant in-LDS scan of S from xs (bit-identical across blocks)
//      + chunk-partial minima of segment averages. 384 blocks.
__global__ __launch_bounds__(256) void k8a(float* __restrict__ ws)
{
  const int bi = blockIdx.x;
  const int c = bi & 7, ib = (bi >> 3) % 6, b = bi / 48;
  const int tid = threadIdx.x;
  const int lane = tid & 63, wav = tid >> 6;

  __shared__ float S[3073];              // S[0..1536] + BIGF pad to 3072
  __shared__ float invl[192];
  __shared__ float wtot[4];

  // scan y = (ROWS - i) - xs[i] -> S (exclusive prefix), same order as before
  {
    const int base = tid * 6;
    const float* xs = ws + WS_XS + b*ROWS;
    float y[6], own = 0.f;
#pragma unroll
    for (int u = 0; u < 6; ++u) {
      y[u] = (float)(ROWS - (base + u)) - xs[base + u];
      own += y[u];
    }
    float v = own;
#pragma unroll
    for (int d = 1; d < 64; d <<= 1) {
      float o = __shfl_up(v, d);
      if (lane >= d) v += o;
    }
    if (lane == 63) wtot[wav] = v;
    __syncthreads();
    float wpre = 0.f;
    for (int w = 0; w < wav; ++w) wpre += wtot[w];
    float run = wpre + (v - own);
#pragma unroll
    for (int u = 0; u < 6; ++u) { S[base + u] = run; run += y[u]; }
    if (tid == 255) S[ROWS] = run;
#pragma unroll
    for (int u = 0; u < 6; ++u) S[ROWS + 1 + base + u] = BIGF;
    if (tid < 192) invl[tid] = 1.0f / (float)(c*192 + tid + 1);
  }
  __syncthreads();

  const int ibase = ib*256;
  const int segbase = ibase + c*192 + 1;
  const float Si = S[ibase + tid];
  float gm = 3.0e38f;
#pragma unroll 8
  for (int k = 0; k < 192; ++k)
    gm = fminf(gm, (S[segbase + tid + k] - Si) * invl[k]);
  ws[WS_GPART + (b*8 + c)*ROWS + ibase + tid] = gm;
}

// --------- K8b: reduce partials, prefix-max (isotonic), final ranks ----------
__global__ __launch_bounds__(768) void k8b(float* __restrict__ ws,
                                           float* __restrict__ out)
{
  const int b = blockIdx.x, tid = threadIdx.x;
  const int lane = tid & 63, wav = tid >> 6;
  __shared__ float g[ROWS];
  __shared__ float wtot[12];
  for (int t = tid; t < ROWS; t += 768) {
    float gm = 3.0e38f;
#pragma unroll
    for (int c = 0; c < 8; ++c)
      gm = fminf(gm, ws[WS_GPART + (b*8 + c)*ROWS + t]);
    g[t] = gm;
  }
  __syncthreads();
  const float a = g[2*tid], cc = g[2*tid + 1];
  float v = fmaxf(a, cc);
#pragma unroll
  for (int d = 1; d < 64; d <<= 1) {
    float o = __shfl_up(v, d);
    if (lane >= d) v = fmaxf(v, o);
  }
  if (lane == 63) wtot[wav] = v;
  __syncthreads();
  float wpre = -3.0e38f;
  for (int w = 0; w < wav; ++w) wpre = fmaxf(wpre, wtot[w]);
  float lex = __shfl_up(v, 1);
  if (lane == 0) lex = -3.0e38f;
  const float excl = fmaxf(wpre, lex);
  const float i0 = fmaxf(excl, a);
  const float i1 = fmaxf(i0, cc);
  g[2*tid] = i0; g[2*tid + 1] = i1;
  __syncthreads();
  const float* xs = ws + WS_XS + b*ROWS;
  const int* desc = reinterpret_cast<const int*>(ws) + WS_DESC + b*ROWS;
  for (int t = tid; t < ROWS; t += 768) {
    const int dr = desc[t];
    out[b*ROWS + t] = xs[dr] + g[dr];
  }
}

extern "C" void kernel_launch(void* const* d_in, const int* in_sizes, int n_in,
                              void* d_out, int out_size, void* d_ws, size_t ws_size,
                              hipStream_t stream) {
  const float* table = (const float*)d_in[0];
  const float* w1  = (const float*)d_in[1];
  const float* b1  = (const float*)d_in[2];
  const float* w2  = (const float*)d_in[3];
  const float* b2  = (const float*)d_in[4];
  const float* mw  = (const float*)d_in[5];
  const float* mb  = (const float*)d_in[6];
  const float* dw1 = (const float*)d_in[7];
  const float* db1 = (const float*)d_in[8];
  const float* dw2 = (const float*)d_in[9];
  const float* db2 = (const float*)d_in[10];
  const int* labels = (const int*)d_in[11];
  const int* bsp    = (const int*)d_in[12];
  float* out = (float*)d_out;
  float* ws  = (float*)d_ws;

  k1_ae<<<768, 256, 0, stream>>>(table, w1, b1, w2, b2, mw, mb, dw1, db1, dw2, db2, labels, ws);
  kranks<<<192, 256, 0, stream>>>(labels, bsp, ws, out);
  k8a<<<384, 256, 0, stream>>>(ws);
  k8b<<<8, 768, 0, stream>>>(ws, out);
}